// Round 7
// baseline (75.980 us; speedup 1.0000x reference)
//
#include <hip/hip_runtime.h>
#include <math.h>

#define B_ 4
#define N_ 256
#define DE_ 128
#define DV_ 64
#define EPS_ 1e-5f

// expansion-block geometry (kernel B, blocks >= 1024)
#define NEXP_Z 1232           // zhat linear-sweep blocks
#define NEXP_Q 304            // qij upper-tri zero blocks
#define CH_Z   6810           // quads per zhat block  (1232*6810 >= 8388608)
#define CH_Q   13798          // quads per qij block   (304*13798 >= 4194304)

typedef __attribute__((ext_vector_type(4))) float f32x4;

__device__ __forceinline__ f32x4 ld4(const float* p) { return *(const f32x4*)p; }
__device__ __forceinline__ void st4(float* p, f32x4 v) { *(f32x4*)p = v; }
__device__ __forceinline__ void nt4(float* p, f32x4 v) { __builtin_nontemporal_store(v, (f32x4*)p); }

// ---------------- workspace layout (float offsets) ----------------
#define OFF_ETA   0
#define OFF_G     64
#define OFF_MR    128
#define OFF_MI    192
#define OFF_KER   256
#define OFF_KEI   (OFF_KER + N_*DV_)
#define OFF_A     (OFF_KEI + N_*DV_)      // Vij^(-|tau|)
#define OFF_INV   (OFF_A + N_*DV_)        // 1/(Vij+lamGa)
#define OFF_QR    (OFF_INV + N_*DV_)
#define OFF_QI    (OFF_QR + B_*N_*DV_)
#define OFF_KR    (OFF_QI + B_*N_*DV_)
#define OFF_KI    (OFF_KR + B_*N_*DV_)
#define OFF_VR    (OFF_KI + B_*N_*DV_)
#define OFF_VI    (OFF_VR + B_*N_*DV_)

// ---------------- output layout ----------------
#define OUT_EL    0
#define OUT_OUT   (B_*2*N_*DV_)
#define OUT_QIJ   (OUT_OUT + B_*2*N_*DE_)
#define OUT_ZHAT  (OUT_QIJ + B_*N_*N_*DV_)
#define OUT_LAMH  (OUT_ZHAT + (size_t)B_*2*N_*N_*DV_)

// =====================================================================
// Kernel A: blocks 0..255 = QKV projections; 256..319 = per-delta tables.
// =====================================================================
__global__ __launch_bounds__(256) void k_pre(
    const float* __restrict__ Zq, const float* __restrict__ Zk, const float* __restrict__ Zv,
    const float* __restrict__ Wqr, const float* __restrict__ Wqi,
    const float* __restrict__ bqr, const float* __restrict__ bqi,
    const float* __restrict__ Wkr, const float* __restrict__ Wki,
    const float* __restrict__ bkr, const float* __restrict__ bki,
    const float* __restrict__ Wvr, const float* __restrict__ Wvi,
    const float* __restrict__ bvr, const float* __restrict__ bvi,
    const float* __restrict__ t,  const float* __restrict__ lam1,
    const float* __restrict__ lOm, const float* __restrict__ lGa,
    const float* __restrict__ eta_p, const float* __restrict__ tau_p,
    float* __restrict__ ws, float* __restrict__ out)
{
    const int tid = (int)threadIdx.x;
    const int wv = tid >> 6;
    const int d = tid & 63;

    if (blockIdx.x >= 256) {
        const int idx = (int)blockIdx.x - 256;
        const int delta = idx * 4 + wv;

        const float l0 = lam1[d & 31];
        const float re = -l0 * l0;
        const float im = (d < 32) ? lam1[32 + d] : -lam1[d];

        const float lo = lOm[d];
        const float lam_Om = lo * lo;
        const float lg_ = lGa[d];
        const float lam_Ga = lg_ * lg_ + EPS_;
        const float tau_a = fabsf(tau_p[0]);

        const float t0 = t[0];
        const float dt = t[delta] - t0;

        const float amp = expf(re * dt);
        const float ph  = im * dt;
        const int td = delta * DV_ + d;
        ws[OFF_KER + td] = amp * cosf(ph);
        ws[OFF_KEI + td] = amp * sinf(ph);

        const float e2  = expf(2.0f * re * dt);
        const float vij = lam_Ga * e2 + lam_Om * (e2 - 1.0f) / (2.0f * (re - EPS_));
        ws[OFF_A   + td] = expf(-tau_a * logf(vij));
        ws[OFF_INV + td] = 1.0f / (vij + lam_Ga);

        if (delta == 0) {
            const float eta = 1.0f / (1.0f + expf(-eta_p[d]));
            const float g   = 1.0f / (1.0f + expf(-eta));
            ws[OFF_ETA + d] = eta;
            ws[OFF_G   + d] = g;
            const float h  = t[1] - t0;
            const float ma = expf(re * h);
            ws[OFF_MR + d] = ma * cosf(im * h);
            ws[OFF_MI + d] = ma * sinf(im * h);
            out[OUT_LAMH + d]       = re;
            out[OUT_LAMH + DV_ + d] = im;
        }
        return;
    }

    const int row0 = (int)blockIdx.x * 4;
    const int b = row0 >> 8;
    const int n0 = row0 & (N_ - 1);

    __shared__ float x[4][6][DE_];
    #pragma unroll
    for (int it = 0; it < 3; ++it) {
        const int v = tid + it * 256;
        const int seg = v >> 5;
        const int pos = v & 31;
        const int r = seg & 3;
        const int a = seg >> 2;
        const int m = a >> 1;
        const int c = a & 1;
        const float* src = (m == 0) ? Zq : ((m == 1) ? Zk : Zv);
        const f32x4 val = ld4(src + ((size_t)(b*2 + c)*N_ + (n0 + r))*DE_ + pos*4);
        st4(&x[r][a][pos*4], val);
    }
    __syncthreads();

    const int row = row0 + wv;
    float aqr = 0.f, aqi = 0.f, akr = 0.f, aki = 0.f, avr = 0.f, avi = 0.f;
    #pragma unroll 8
    for (int k = 0; k < DE_; ++k) {
        const float xqr = x[wv][0][k], xqi = x[wv][1][k];
        const float xkr = x[wv][2][k], xki = x[wv][3][k];
        const float xvr = x[wv][4][k], xvi = x[wv][5][k];
        float wr, wi;
        wr = Wqr[k*DV_ + d]; wi = Wqi[k*DV_ + d];
        aqr += xqr*wr - xqi*wi; aqi += xqr*wi + xqi*wr;
        wr = Wkr[k*DV_ + d]; wi = Wki[k*DV_ + d];
        akr += xkr*wr - xki*wi; aki += xkr*wi + xki*wr;
        wr = Wvr[k*DV_ + d]; wi = Wvi[k*DV_ + d];
        avr += xvr*wr - xvi*wi; avi += xvr*wi + xvi*wr;
    }
    const int o = row * DV_ + d;
    ws[OFF_QR + o] = aqr + bqr[d];
    ws[OFF_QI + o] = aqi + bqi[d];
    ws[OFF_KR + o] = akr + bkr[d];
    ws[OFF_KI + o] = aki + bki[d];
    ws[OFF_VR + o] = avr + bvr[d];
    ws[OFF_VI + o] = avi + bvi[d];
}

// =====================================================================
// Kernel B:
//   blocks 0..1023        : stats per (b,i) — P1 (no stores), P3 Qij
//                           triangle (NT), epilogue (est_latent/out).
//   blocks 1024..1024+NZ-1: Zhat full-tensor linear sweep (incl. zeros),
//                           fill-style: contiguous chunk, cached stores.
//   remaining blocks      : Qij upper-triangle zero sweep (cached).
// =====================================================================
__global__ __launch_bounds__(256) void k_main2(
    const float* __restrict__ ws, float* __restrict__ out,
    const float* __restrict__ Wpr, const float* __restrict__ Wpi,
    const float* __restrict__ bpr, const float* __restrict__ bpi,
    const float* __restrict__ nf_p, const float* __restrict__ tau_p,
    const float* __restrict__ nu_p)
{
    const int vb = (int)blockIdx.x;
    const int tid = (int)threadIdx.x;

    __shared__ float wl[N_];
    __shared__ f32x4 redS[4][16];
    __shared__ f32x4 redR[4][16];
    __shared__ f32x4 redI[4][16];
    __shared__ float ppr_s[DV_], ppi_s[DV_];

    if (vb >= 1024) {
        // ---------------- expansion blocks: pure linear streaming ----------------
        const f32x4 z4 = {0.f,0.f,0.f,0.f};
        const int eb = vb - 1024;
        if (eb < NEXP_Z) {
            long long u0 = (long long)eb * CH_Z;
            long long ue = u0 + CH_Z; if (ue > 8388608LL) ue = 8388608LL;
            for (long long u = u0 + tid; u < ue; u += 256) {
                const int ui  = (int)u;
                const int dqi = ui & 15;
                const int j   = (ui >> 4) & 255;
                const int ii  = (ui >> 12) & 255;
                const int bc  = ui >> 20;
                const int bb  = bc >> 1, cc = bc & 1;
                const int delta = ii - j;
                const int td = (delta > 0 ? delta : 0)*DV_ + dqi*4;
                const f32x4 ker = ld4(ws + OFF_KER + td);
                const f32x4 kei = ld4(ws + OFF_KEI + td);
                const int kj = (bb*N_ + j)*DV_ + dqi*4;
                const f32x4 vr = ld4(ws + OFF_VR + kj);
                const f32x4 vi = ld4(ws + OFF_VI + kj);
                f32x4 z = (cc == 0) ? (ker*vr - kei*vi) : (ker*vi + kei*vr);
                if (delta < 0) z = z4;
                st4(out + OUT_ZHAT + (size_t)u*4, z);
            }
        } else {
            const int qb = eb - NEXP_Z;
            long long u0 = (long long)qb * CH_Q;
            long long ue = u0 + CH_Q; if (ue > 4194304LL) ue = 4194304LL;
            for (long long u = u0 + tid; u < ue; u += 256) {
                const int ui = (int)u;
                const int j  = (ui >> 4) & 255;
                const int ii = (ui >> 12) & 255;
                if (j > ii) st4(out + OUT_QIJ + (size_t)u*4, z4);
            }
        }
        return;
    }

    // ---------------- stats blocks ----------------
    const int b = vb & 3;
    const int i = (N_ - 1) - (vb >> 2);     // heavy rows dispatch first
    const int row = b * N_ + i;
    const int wv = tid >> 6;
    const int l = tid & 63;
    const int g = l >> 4;
    const int q16 = l & 15;
    const int dq = q16 * 4;

    const float nf    = nf_p[0];
    const float tau_a = fabsf(tau_p[0]);
    const float nu_a  = fabsf(nu_p[0]);

    const f32x4 qr4 = ld4(ws + OFF_QR + row*DV_ + dq);
    const f32x4 qi4 = ld4(ws + OFF_QI + row*DV_ + dq);

    const int nfull = (i + 1) >> 2;
    const int tail  = (i + 1) & 3;

    float* qij = out + OUT_QIJ + (size_t)row * N_ * DV_;

    // ---- P1: dist -> w[j]; accumulate Z and ev (no stores) ----
    f32x4 s4  = {0.f,0.f,0.f,0.f};
    f32x4 evr = {0.f,0.f,0.f,0.f};
    f32x4 evi = {0.f,0.f,0.f,0.f};
    #pragma unroll 2
    for (int T = wv; T < nfull; T += 4) {
        const int j = 4*T + g;
        const int td = (i - j)*DV_ + dq;
        const f32x4 ker = ld4(ws + OFF_KER + td);
        const f32x4 kei = ld4(ws + OFF_KEI + td);
        const f32x4 vnv = ld4(ws + OFF_INV + td);
        const f32x4 a4  = ld4(ws + OFF_A   + td);
        const int kj = (b*N_ + j)*DV_ + dq;
        const f32x4 kr = ld4(ws + OFF_KR + kj);
        const f32x4 ki = ld4(ws + OFF_KI + kj);
        const f32x4 vr = ld4(ws + OFF_VR + kj);
        const f32x4 vi = ld4(ws + OFF_VI + kj);
        const f32x4 rr = qr4 - (ker*kr - kei*ki);
        const f32x4 ri = qi4 - (ker*ki + kei*kr);
        const f32x4 mah = (rr*rr + ri*ri) * vnv;
        float ds = mah[0] + mah[1] + mah[2] + mah[3];
        ds += __shfl_xor(ds, 1);
        ds += __shfl_xor(ds, 2);
        ds += __shfl_xor(ds, 4);
        ds += __shfl_xor(ds, 8);
        const float wj = expf(-tau_a * logf(nf + nu_a*ds + EPS_));
        if (q16 == 0) wl[j] = wj;
        const f32x4 zr = ker*vr - kei*vi;
        const f32x4 zi = ker*vi + kei*vr;
        const f32x4 qn = a4 * wj;
        s4  += qn;
        evr += qn * zr;
        evi += qn * zi;
    }
    if (tail && ((nfull & 3) == wv)) {
        const int j = 4*nfull + g;
        const bool act = (g < tail);
        const int td = (act ? (i - j) : 0)*DV_ + dq;
        const f32x4 ker = ld4(ws + OFF_KER + td);
        const f32x4 kei = ld4(ws + OFF_KEI + td);
        const f32x4 vnv = ld4(ws + OFF_INV + td);
        const f32x4 a4  = ld4(ws + OFF_A   + td);
        const int kj = (b*N_ + (act ? j : 0))*DV_ + dq;
        const f32x4 kr = ld4(ws + OFF_KR + kj);
        const f32x4 ki = ld4(ws + OFF_KI + kj);
        const f32x4 vr = ld4(ws + OFF_VR + kj);
        const f32x4 vi = ld4(ws + OFF_VI + kj);
        const f32x4 rr = qr4 - (ker*kr - kei*ki);
        const f32x4 ri = qi4 - (ker*ki + kei*kr);
        const f32x4 mah = (rr*rr + ri*ri) * vnv;
        float ds = mah[0] + mah[1] + mah[2] + mah[3];
        ds += __shfl_xor(ds, 1);
        ds += __shfl_xor(ds, 2);
        ds += __shfl_xor(ds, 4);
        ds += __shfl_xor(ds, 8);
        if (act) {
            const float wj = expf(-tau_a * logf(nf + nu_a*ds + EPS_));
            if (q16 == 0) wl[j] = wj;
            const f32x4 zr = ker*vr - kei*vi;
            const f32x4 zi = ker*vi + kei*vr;
            const f32x4 qn = a4 * wj;
            s4  += qn;
            evr += qn * zr;
            evi += qn * zi;
        }
    }

    #pragma unroll
    for (int mask = 16; mask <= 32; mask <<= 1) {
        #pragma unroll
        for (int c = 0; c < 4; ++c) {
            s4[c]  += __shfl_xor(s4[c],  mask);
            evr[c] += __shfl_xor(evr[c], mask);
            evi[c] += __shfl_xor(evi[c], mask);
        }
    }
    if (g == 0) { redS[wv][q16] = s4; redR[wv][q16] = evr; redI[wv][q16] = evi; }
    __syncthreads();
    const f32x4 Z = redS[0][q16] + redS[1][q16] + redS[2][q16] + redS[3][q16];
    const f32x4 one = {1.f,1.f,1.f,1.f};
    const f32x4 invZ = one / Z;

    // ---- P3: Qij triangle (NT stores) ----
    #pragma unroll 2
    for (int T = wv; T < nfull; T += 4) {
        const int j = 4*T + g;
        const int o = j*DV_ + dq;
        const int td = (i - j)*DV_ + dq;
        const f32x4 q4 = ld4(ws + OFF_A + td) * wl[j] * invZ;
        nt4(qij + o, q4);
    }
    if (tail && ((nfull & 3) == wv) && (g < tail)) {
        const int j = 4*nfull + g;
        const int o = j*DV_ + dq;
        const int td = (i - j)*DV_ + dq;
        const f32x4 q4 = ld4(ws + OFF_A + td) * wl[j] * invZ;
        nt4(qij + o, q4);
    }

    // ---- epilogue: est_latent + pp ----
    if (tid < 16) {
        const f32x4 Zt = redS[0][tid] + redS[1][tid] + redS[2][tid] + redS[3][tid];
        const f32x4 iZ = one / Zt;
        const f32x4 Evr = (redR[0][tid] + redR[1][tid] + redR[2][tid] + redR[3][tid]) * iZ;
        const f32x4 Evi = (redI[0][tid] + redI[1][tid] + redI[2][tid] + redI[3][tid]) * iZ;
        const int dq2 = tid * 4;
        const f32x4 vr  = ld4(ws + OFF_VR + row*DV_ + dq2);
        const f32x4 vi  = ld4(ws + OFF_VI + row*DV_ + dq2);
        const f32x4 eta = ld4(ws + OFF_ETA + dq2);
        const f32x4 gg  = ld4(ws + OFF_G + dq2);
        const f32x4 elr = (1.0f - eta)*vr + gg*Evr;
        const f32x4 eli = (1.0f - eta)*vi + gg*Evi;
        st4(out + OUT_EL + ((size_t)(b*2+0)*N_ + i)*DV_ + dq2, elr);
        st4(out + OUT_EL + ((size_t)(b*2+1)*N_ + i)*DV_ + dq2, eli);
        const f32x4 mr = ld4(ws + OFF_MR + dq2);
        const f32x4 mi = ld4(ws + OFF_MI + dq2);
        st4(ppr_s + dq2, mr*elr - mi*eli);
        st4(ppi_s + dq2, mr*eli + mi*elr);
    }
    __syncthreads();

    // ---- fused output projection ----
    if (tid < DE_) {
        const int e = tid;
        float ar = bpr[e], ai = bpi[e];
        #pragma unroll 8
        for (int dd = 0; dd < DV_; ++dd) {
            const float wr = Wpr[dd*DE_ + e], wi = Wpi[dd*DE_ + e];
            const float r = ppr_s[dd], im = ppi_s[dd];
            ar += r*wr - im*wi;
            ai += r*wi + im*wr;
        }
        out[OUT_OUT + ((size_t)(b*2+0)*N_ + i)*DE_ + e] = ar;
        out[OUT_OUT + ((size_t)(b*2+1)*N_ + i)*DE_ + e] = ai;
    }
}

// =====================================================================
extern "C" void kernel_launch(void* const* d_in, const int* in_sizes, int n_in,
                              void* d_out, int out_size, void* d_ws, size_t ws_size,
                              hipStream_t stream)
{
    const float* Zq   = (const float*)d_in[0];
    const float* Zk   = (const float*)d_in[1];
    const float* Zv   = (const float*)d_in[2];
    const float* t    = (const float*)d_in[3];
    const float* Wqr  = (const float*)d_in[4];
    const float* Wqi  = (const float*)d_in[5];
    const float* bqr  = (const float*)d_in[6];
    const float* bqi  = (const float*)d_in[7];
    const float* Wkr  = (const float*)d_in[8];
    const float* Wki  = (const float*)d_in[9];
    const float* bkr  = (const float*)d_in[10];
    const float* bki  = (const float*)d_in[11];
    const float* Wvr  = (const float*)d_in[12];
    const float* Wvi  = (const float*)d_in[13];
    const float* bvr  = (const float*)d_in[14];
    const float* bvi  = (const float*)d_in[15];
    const float* Wpr  = (const float*)d_in[16];
    const float* Wpi  = (const float*)d_in[17];
    const float* bpr  = (const float*)d_in[18];
    const float* bpi  = (const float*)d_in[19];
    const float* lam1 = (const float*)d_in[20];
    const float* lOm  = (const float*)d_in[21];
    const float* lGa  = (const float*)d_in[22];
    const float* nf   = (const float*)d_in[23];
    const float* tau  = (const float*)d_in[24];
    const float* nu   = (const float*)d_in[25];
    const float* etap = (const float*)d_in[26];

    float* ws  = (float*)d_ws;
    float* out = (float*)d_out;

    k_pre<<<256 + 64, 256, 0, stream>>>(Zq, Zk, Zv,
                                        Wqr, Wqi, bqr, bqi,
                                        Wkr, Wki, bkr, bki,
                                        Wvr, Wvi, bvr, bvi,
                                        t, lam1, lOm, lGa, etap, tau, ws, out);
    k_main2<<<1024 + NEXP_Z + NEXP_Q, 256, 0, stream>>>(ws, out, Wpr, Wpi, bpr, bpi, nf, tau, nu);
}

// Round 8
// 64.717 us; speedup vs baseline: 1.1740x; 1.1740x over previous
//
#include <hip/hip_runtime.h>
#include <math.h>

#define B_ 4
#define N_ 256
#define DE_ 128
#define DV_ 64
#define EPS_ 1e-5f

typedef __attribute__((ext_vector_type(4))) float f32x4;

__device__ __forceinline__ f32x4 ld4(const float* p) { return *(const f32x4*)p; }
__device__ __forceinline__ void st4(float* p, f32x4 v) { *(f32x4*)p = v; }

// ---------------- workspace layout (float offsets) ----------------
#define OFF_ETA   0
#define OFF_G     64
#define OFF_MR    128
#define OFF_MI    192
#define OFF_KER   256
#define OFF_KEI   (OFF_KER + N_*DV_)
#define OFF_A     (OFF_KEI + N_*DV_)      // Vij^(-|tau|)
#define OFF_INV   (OFF_A + N_*DV_)        // 1/(Vij+lamGa)
#define OFF_QR    (OFF_INV + N_*DV_)
#define OFF_QI    (OFF_QR + B_*N_*DV_)
#define OFF_KR    (OFF_QI + B_*N_*DV_)
#define OFF_KI    (OFF_KR + B_*N_*DV_)
#define OFF_VR    (OFF_KI + B_*N_*DV_)
#define OFF_VI    (OFF_VR + B_*N_*DV_)

// ---------------- output layout ----------------
#define OUT_EL    0
#define OUT_OUT   (B_*2*N_*DV_)
#define OUT_QIJ   (OUT_OUT + B_*2*N_*DE_)
#define OUT_ZHAT  (OUT_QIJ + B_*N_*N_*DV_)
#define OUT_LAMH  (OUT_ZHAT + (size_t)B_*2*N_*N_*DV_)

// =====================================================================
// Kernel 1 (R2-proven structure): blocks 0..1023 = QKV projections
// (k-split, 4 waves/block); blocks 1024..1087 = per-delta tables.
// =====================================================================
__global__ __launch_bounds__(256) void k_pre(
    const float* __restrict__ Zq, const float* __restrict__ Zk, const float* __restrict__ Zv,
    const float* __restrict__ Wqr, const float* __restrict__ Wqi,
    const float* __restrict__ bqr, const float* __restrict__ bqi,
    const float* __restrict__ Wkr, const float* __restrict__ Wki,
    const float* __restrict__ bkr, const float* __restrict__ bki,
    const float* __restrict__ Wvr, const float* __restrict__ Wvi,
    const float* __restrict__ bvr, const float* __restrict__ bvi,
    const float* __restrict__ t,  const float* __restrict__ lam1,
    const float* __restrict__ lOm, const float* __restrict__ lGa,
    const float* __restrict__ eta_p, const float* __restrict__ tau_p,
    float* __restrict__ ws, float* __restrict__ out)
{
    const int tid = (int)threadIdx.x;

    if (blockIdx.x >= 1024) {
        // ---------------- tables branch ----------------
        const int idx = (int)blockIdx.x - 1024;
        const int w = tid >> 6;
        const int d = tid & 63;
        const int delta = idx * 4 + w;

        const float l0 = lam1[d & 31];
        const float re = -l0 * l0;
        const float im = (d < 32) ? lam1[32 + d] : -lam1[d];

        const float lo = lOm[d];
        const float lam_Om = lo * lo;
        const float lg_ = lGa[d];
        const float lam_Ga = lg_ * lg_ + EPS_;
        const float tau_a = fabsf(tau_p[0]);

        const float t0 = t[0];
        const float dt = t[delta] - t0;

        const float amp = expf(re * dt);
        const float ph  = im * dt;
        const int td = delta * DV_ + d;
        ws[OFF_KER + td] = amp * cosf(ph);
        ws[OFF_KEI + td] = amp * sinf(ph);

        const float e2  = expf(2.0f * re * dt);
        const float vij = lam_Ga * e2 + lam_Om * (e2 - 1.0f) / (2.0f * (re - EPS_));
        ws[OFF_A   + td] = expf(-tau_a * logf(vij));
        ws[OFF_INV + td] = 1.0f / (vij + lam_Ga);

        if (delta == 0) {
            const float eta = 1.0f / (1.0f + expf(-eta_p[d]));
            const float g   = 1.0f / (1.0f + expf(-eta));
            ws[OFF_ETA + d] = eta;
            ws[OFF_G   + d] = g;
            const float h  = t[1] - t0;
            const float ma = expf(re * h);
            ws[OFF_MR + d] = ma * cosf(im * h);
            ws[OFF_MI + d] = ma * sinf(im * h);
            out[OUT_LAMH + d]       = re;
            out[OUT_LAMH + DV_ + d] = im;
        }
        return;
    }

    // ---------------- QKV branch (k-split across 4 waves) ----------------
    const int row = (int)blockIdx.x;        // b*N + n
    const int b = row >> 8, n = row & (N_ - 1);

    __shared__ float x[6][DE_];
    __shared__ float red[4][6][DV_];

    if (tid < DE_) {
        x[0][tid] = Zq[((size_t)(b*2+0)*N_ + n)*DE_ + tid];
        x[1][tid] = Zq[((size_t)(b*2+1)*N_ + n)*DE_ + tid];
        x[2][tid] = Zk[((size_t)(b*2+0)*N_ + n)*DE_ + tid];
        x[3][tid] = Zk[((size_t)(b*2+1)*N_ + n)*DE_ + tid];
        x[4][tid] = Zv[((size_t)(b*2+0)*N_ + n)*DE_ + tid];
        x[5][tid] = Zv[((size_t)(b*2+1)*N_ + n)*DE_ + tid];
    }
    __syncthreads();

    const int w = tid >> 6;                 // k-chunk: k in [32w, 32w+32)
    const int d = tid & 63;
    float aqr = 0.f, aqi = 0.f, akr = 0.f, aki = 0.f, avr = 0.f, avi = 0.f;
    const int k0 = w * 32;
    #pragma unroll 4
    for (int kk = 0; kk < 32; ++kk) {
        const int k = k0 + kk;
        const float xqr = x[0][k], xqi = x[1][k];
        const float xkr = x[2][k], xki = x[3][k];
        const float xvr = x[4][k], xvi = x[5][k];
        float wr, wi;
        wr = Wqr[k*DV_ + d]; wi = Wqi[k*DV_ + d];
        aqr += xqr*wr - xqi*wi; aqi += xqr*wi + xqi*wr;
        wr = Wkr[k*DV_ + d]; wi = Wki[k*DV_ + d];
        akr += xkr*wr - xki*wi; aki += xkr*wi + xki*wr;
        wr = Wvr[k*DV_ + d]; wi = Wvi[k*DV_ + d];
        avr += xvr*wr - xvi*wi; avi += xvr*wi + xvi*wr;
    }
    red[w][0][d] = aqr; red[w][1][d] = aqi;
    red[w][2][d] = akr; red[w][3][d] = aki;
    red[w][4][d] = avr; red[w][5][d] = avi;
    __syncthreads();

    if (tid < DV_) {
        const int o = row * DV_ + tid;
        ws[OFF_QR + o] = red[0][0][tid]+red[1][0][tid]+red[2][0][tid]+red[3][0][tid] + bqr[tid];
        ws[OFF_QI + o] = red[0][1][tid]+red[1][1][tid]+red[2][1][tid]+red[3][1][tid] + bqi[tid];
        ws[OFF_KR + o] = red[0][2][tid]+red[1][2][tid]+red[2][2][tid]+red[3][2][tid] + bkr[tid];
        ws[OFF_KI + o] = red[0][3][tid]+red[1][3][tid]+red[2][3][tid]+red[3][3][tid] + bki[tid];
        ws[OFF_VR + o] = red[0][4][tid]+red[1][4][tid]+red[2][4][tid]+red[3][4][tid] + bvr[tid];
        ws[OFF_VI + o] = red[0][5][tid]+red[1][5][tid]+red[2][5][tid]+red[3][5][tid] + bvi[tid];
    }
}

// =====================================================================
// Kernel 2: R6 structure EXACTLY, single variable changed: all bulk
// output stores are CACHED (st4) instead of nontemporal. Tests the
// "NT 16B partial-line write" theory against the fill's 6.8 TB/s.
// =====================================================================
__global__ __launch_bounds__(256) void k_main2(
    const float* __restrict__ ws, float* __restrict__ out,
    const float* __restrict__ Wpr, const float* __restrict__ Wpi,
    const float* __restrict__ bpr, const float* __restrict__ bpi,
    const float* __restrict__ nf_p, const float* __restrict__ tau_p,
    const float* __restrict__ nu_p)
{
    const int vb = (int)blockIdx.x;
    const int b = vb & 3;
    const int i = (N_ - 1) - (vb >> 2);     // heavy rows dispatch first
    const int row = b * N_ + i;
    const int tid = (int)threadIdx.x;
    const int wv = tid >> 6;
    const int l = tid & 63;
    const int g = l >> 4;
    const int q16 = l & 15;
    const int dq = q16 * 4;

    __shared__ float wl[N_];
    __shared__ f32x4 redS[4][16];
    __shared__ f32x4 redR[4][16];
    __shared__ f32x4 redI[4][16];
    __shared__ float ppr_s[DV_], ppi_s[DV_];

    const float nf    = nf_p[0];
    const float tau_a = fabsf(tau_p[0]);
    const float nu_a  = fabsf(nu_p[0]);

    const f32x4 qr4 = ld4(ws + OFF_QR + row*DV_ + dq);
    const f32x4 qi4 = ld4(ws + OFF_QI + row*DV_ + dq);

    const int nfull = (i + 1) >> 2;
    const int tail  = (i + 1) & 3;
    const f32x4 z4 = {0.f,0.f,0.f,0.f};

    float* qij = out + OUT_QIJ + (size_t)row * N_ * DV_;
    float* zro = out + OUT_ZHAT + ((size_t)(b*2+0)*N_ + i) * N_ * DV_;
    float* zio = out + OUT_ZHAT + ((size_t)(b*2+1)*N_ + i) * N_ * DV_;

    // ---- P1: dist -> w[j]; Zhat stream; accumulate Z and ev ----
    f32x4 s4  = {0.f,0.f,0.f,0.f};
    f32x4 evr = {0.f,0.f,0.f,0.f};
    f32x4 evi = {0.f,0.f,0.f,0.f};
    #pragma unroll 2
    for (int T = wv; T < nfull; T += 4) {
        const int j = 4*T + g;
        const int o = j*DV_ + dq;
        const int td = (i - j)*DV_ + dq;
        const f32x4 ker = ld4(ws + OFF_KER + td);
        const f32x4 kei = ld4(ws + OFF_KEI + td);
        const f32x4 vnv = ld4(ws + OFF_INV + td);
        const f32x4 a4  = ld4(ws + OFF_A   + td);
        const int kj = (b*N_ + j)*DV_ + dq;
        const f32x4 kr = ld4(ws + OFF_KR + kj);
        const f32x4 ki = ld4(ws + OFF_KI + kj);
        const f32x4 vr = ld4(ws + OFF_VR + kj);
        const f32x4 vi = ld4(ws + OFF_VI + kj);
        const f32x4 rr = qr4 - (ker*kr - kei*ki);
        const f32x4 ri = qi4 - (ker*ki + kei*kr);
        const f32x4 mah = (rr*rr + ri*ri) * vnv;
        float ds = mah[0] + mah[1] + mah[2] + mah[3];
        ds += __shfl_xor(ds, 1);
        ds += __shfl_xor(ds, 2);
        ds += __shfl_xor(ds, 4);
        ds += __shfl_xor(ds, 8);
        const float wj = expf(-tau_a * logf(nf + nu_a*ds + EPS_));
        if (q16 == 0) wl[j] = wj;
        const f32x4 zr = ker*vr - kei*vi;
        const f32x4 zi = ker*vi + kei*vr;
        st4(zro + o, zr);
        st4(zio + o, zi);
        const f32x4 qn = a4 * wj;
        s4  += qn;
        evr += qn * zr;
        evi += qn * zi;
    }
    if (tail && ((nfull & 3) == wv)) {
        const int j = 4*nfull + g;
        const int o = j*DV_ + dq;
        const bool act = (g < tail);
        const int td = (act ? (i - j) : 0)*DV_ + dq;
        const f32x4 ker = ld4(ws + OFF_KER + td);
        const f32x4 kei = ld4(ws + OFF_KEI + td);
        const f32x4 vnv = ld4(ws + OFF_INV + td);
        const f32x4 a4  = ld4(ws + OFF_A   + td);
        const int kj = (b*N_ + (act ? j : 0))*DV_ + dq;
        const f32x4 kr = ld4(ws + OFF_KR + kj);
        const f32x4 ki = ld4(ws + OFF_KI + kj);
        const f32x4 vr = ld4(ws + OFF_VR + kj);
        const f32x4 vi = ld4(ws + OFF_VI + kj);
        const f32x4 rr = qr4 - (ker*kr - kei*ki);
        const f32x4 ri = qi4 - (ker*ki + kei*kr);
        const f32x4 mah = (rr*rr + ri*ri) * vnv;
        float ds = mah[0] + mah[1] + mah[2] + mah[3];
        ds += __shfl_xor(ds, 1);
        ds += __shfl_xor(ds, 2);
        ds += __shfl_xor(ds, 4);
        ds += __shfl_xor(ds, 8);
        if (act) {
            const float wj = expf(-tau_a * logf(nf + nu_a*ds + EPS_));
            if (q16 == 0) wl[j] = wj;
            const f32x4 zr = ker*vr - kei*vi;
            const f32x4 zi = ker*vi + kei*vr;
            st4(zro + o, zr);
            st4(zio + o, zi);
            const f32x4 qn = a4 * wj;
            s4  += qn;
            evr += qn * zr;
            evi += qn * zi;
        } else {
            st4(zro + o, z4);
            st4(zio + o, z4);
        }
    }
    // Zhat zero region (store-only)
    {
        const int jz0 = 4 * (nfull + (tail ? 1 : 0));
        const int nq = (N_ - jz0) * 16;
        for (int u = tid; u < nq; u += 256) {
            const int o = jz0*DV_ + u*4;
            st4(zro + o, z4);
            st4(zio + o, z4);
        }
    }

    // reduce s4 / evr / evi across the 4 g-slots then across waves
    #pragma unroll
    for (int mask = 16; mask <= 32; mask <<= 1) {
        #pragma unroll
        for (int c = 0; c < 4; ++c) {
            s4[c]  += __shfl_xor(s4[c],  mask);
            evr[c] += __shfl_xor(evr[c], mask);
            evi[c] += __shfl_xor(evi[c], mask);
        }
    }
    if (g == 0) { redS[wv][q16] = s4; redR[wv][q16] = evr; redI[wv][q16] = evi; }
    __syncthreads();
    const f32x4 Z = redS[0][q16] + redS[1][q16] + redS[2][q16] + redS[3][q16];
    const f32x4 one = {1.f,1.f,1.f,1.f};
    const f32x4 invZ = one / Z;

    // ---- P3: Qij stream ----
    #pragma unroll 2
    for (int T = wv; T < nfull; T += 4) {
        const int j = 4*T + g;
        const int o = j*DV_ + dq;
        const int td = (i - j)*DV_ + dq;
        const f32x4 q4 = ld4(ws + OFF_A + td) * wl[j] * invZ;
        st4(qij + o, q4);
    }
    if (tail && ((nfull & 3) == wv)) {
        const int j = 4*nfull + g;
        const int o = j*DV_ + dq;
        if (g < tail) {
            const int td = (i - j)*DV_ + dq;
            const f32x4 q4 = ld4(ws + OFF_A + td) * wl[j] * invZ;
            st4(qij + o, q4);
        } else {
            st4(qij + o, z4);
        }
    }
    // Qij zero region
    {
        const int jz0 = 4 * (nfull + (tail ? 1 : 0));
        const int nq = (N_ - jz0) * 16;
        for (int u = tid; u < nq; u += 256) {
            st4(qij + jz0*DV_ + u*4, z4);
        }
    }

    // ---- epilogue: est_latent + pp ----
    if (tid < 16) {
        const f32x4 Zt = redS[0][tid] + redS[1][tid] + redS[2][tid] + redS[3][tid];
        const f32x4 iZ = one / Zt;
        const f32x4 Evr = (redR[0][tid] + redR[1][tid] + redR[2][tid] + redR[3][tid]) * iZ;
        const f32x4 Evi = (redI[0][tid] + redI[1][tid] + redI[2][tid] + redI[3][tid]) * iZ;
        const int dq2 = tid * 4;
        const f32x4 vr  = ld4(ws + OFF_VR + row*DV_ + dq2);
        const f32x4 vi  = ld4(ws + OFF_VI + row*DV_ + dq2);
        const f32x4 eta = ld4(ws + OFF_ETA + dq2);
        const f32x4 gg  = ld4(ws + OFF_G + dq2);
        const f32x4 elr = (1.0f - eta)*vr + gg*Evr;
        const f32x4 eli = (1.0f - eta)*vi + gg*Evi;
        st4(out + OUT_EL + ((size_t)(b*2+0)*N_ + i)*DV_ + dq2, elr);
        st4(out + OUT_EL + ((size_t)(b*2+1)*N_ + i)*DV_ + dq2, eli);
        const f32x4 mr = ld4(ws + OFF_MR + dq2);
        const f32x4 mi = ld4(ws + OFF_MI + dq2);
        st4(ppr_s + dq2, mr*elr - mi*eli);
        st4(ppi_s + dq2, mr*eli + mi*elr);
    }
    __syncthreads();

    // ---- fused output projection ----
    if (tid < DE_) {
        const int e = tid;
        float ar = bpr[e], ai = bpi[e];
        #pragma unroll 8
        for (int dd = 0; dd < DV_; ++dd) {
            const float wr = Wpr[dd*DE_ + e], wi = Wpi[dd*DE_ + e];
            const float r = ppr_s[dd], im = ppi_s[dd];
            ar += r*wr - im*wi;
            ai += r*wi + im*wr;
        }
        out[OUT_OUT + ((size_t)(b*2+0)*N_ + i)*DE_ + e] = ar;
        out[OUT_OUT + ((size_t)(b*2+1)*N_ + i)*DE_ + e] = ai;
    }
}

// =====================================================================
extern "C" void kernel_launch(void* const* d_in, const int* in_sizes, int n_in,
                              void* d_out, int out_size, void* d_ws, size_t ws_size,
                              hipStream_t stream)
{
    const float* Zq   = (const float*)d_in[0];
    const float* Zk   = (const float*)d_in[1];
    const float* Zv   = (const float*)d_in[2];
    const float* t    = (const float*)d_in[3];
    const float* Wqr  = (const float*)d_in[4];
    const float* Wqi  = (const float*)d_in[5];
    const float* bqr  = (const float*)d_in[6];
    const float* bqi  = (const float*)d_in[7];
    const float* Wkr  = (const float*)d_in[8];
    const float* Wki  = (const float*)d_in[9];
    const float* bkr  = (const float*)d_in[10];
    const float* bki  = (const float*)d_in[11];
    const float* Wvr  = (const float*)d_in[12];
    const float* Wvi  = (const float*)d_in[13];
    const float* bvr  = (const float*)d_in[14];
    const float* bvi  = (const float*)d_in[15];
    const float* Wpr  = (const float*)d_in[16];
    const float* Wpi  = (const float*)d_in[17];
    const float* bpr  = (const float*)d_in[18];
    const float* bpi  = (const float*)d_in[19];
    const float* lam1 = (const float*)d_in[20];
    const float* lOm  = (const float*)d_in[21];
    const float* lGa  = (const float*)d_in[22];
    const float* nf   = (const float*)d_in[23];
    const float* tau  = (const float*)d_in[24];
    const float* nu   = (const float*)d_in[25];
    const float* etap = (const float*)d_in[26];

    float* ws  = (float*)d_ws;
    float* out = (float*)d_out;

    k_pre<<<1024 + 64, 256, 0, stream>>>(Zq, Zk, Zv,
                                         Wqr, Wqi, bqr, bqi,
                                         Wkr, Wki, bkr, bki,
                                         Wvr, Wvi, bvr, bvi,
                                         t, lam1, lOm, lGa, etap, tau, ws, out);
    k_main2<<<B_*N_, 256, 0, stream>>>(ws, out, Wpr, Wpi, bpr, bpi, nf, tau, nu);
}

// Round 9
// 63.240 us; speedup vs baseline: 1.2015x; 1.0234x over previous
//
#include <hip/hip_runtime.h>
#include <math.h>

#define B_ 4
#define N_ 256
#define DE_ 128
#define DV_ 64
#define EPS_ 1e-5f

typedef __attribute__((ext_vector_type(4))) float f32x4;

__device__ __forceinline__ f32x4 ld4(const float* p) { return *(const f32x4*)p; }
__device__ __forceinline__ void st4(float* p, f32x4 v) { *(f32x4*)p = v; }

// ---------------- workspace layout (float offsets) ----------------
#define OFF_ETA   0
#define OFF_G     64
#define OFF_MR    128
#define OFF_MI    192
#define OFF_KER   256
#define OFF_KEI   (OFF_KER + N_*DV_)
#define OFF_A     (OFF_KEI + N_*DV_)      // Vij^(-|tau|)
#define OFF_INV   (OFF_A + N_*DV_)        // 1/(Vij+lamGa)
#define OFF_QR    (OFF_INV + N_*DV_)
#define OFF_QI    (OFF_QR + B_*N_*DV_)
#define OFF_KR    (OFF_QI + B_*N_*DV_)
#define OFF_KI    (OFF_KR + B_*N_*DV_)
#define OFF_VR    (OFF_KI + B_*N_*DV_)
#define OFF_VI    (OFF_VR + B_*N_*DV_)

// ---------------- output layout ----------------
#define OUT_EL    0
#define OUT_OUT   (B_*2*N_*DV_)
#define OUT_QIJ   (OUT_OUT + B_*2*N_*DE_)
#define OUT_ZHAT  (OUT_QIJ + B_*N_*N_*DV_)
#define OUT_LAMH  (OUT_ZHAT + (size_t)B_*2*N_*N_*DV_)

// =====================================================================
// Kernel 1 (R2-proven structure): blocks 0..1023 = QKV projections
// (k-split, 4 waves/block); blocks 1024..1087 = per-delta tables.
// =====================================================================
__global__ __launch_bounds__(256) void k_pre(
    const float* __restrict__ Zq, const float* __restrict__ Zk, const float* __restrict__ Zv,
    const float* __restrict__ Wqr, const float* __restrict__ Wqi,
    const float* __restrict__ bqr, const float* __restrict__ bqi,
    const float* __restrict__ Wkr, const float* __restrict__ Wki,
    const float* __restrict__ bkr, const float* __restrict__ bki,
    const float* __restrict__ Wvr, const float* __restrict__ Wvi,
    const float* __restrict__ bvr, const float* __restrict__ bvi,
    const float* __restrict__ t,  const float* __restrict__ lam1,
    const float* __restrict__ lOm, const float* __restrict__ lGa,
    const float* __restrict__ eta_p, const float* __restrict__ tau_p,
    float* __restrict__ ws, float* __restrict__ out)
{
    const int tid = (int)threadIdx.x;

    if (blockIdx.x >= 1024) {
        // ---------------- tables branch ----------------
        const int idx = (int)blockIdx.x - 1024;
        const int w = tid >> 6;
        const int d = tid & 63;
        const int delta = idx * 4 + w;

        const float l0 = lam1[d & 31];
        const float re = -l0 * l0;
        const float im = (d < 32) ? lam1[32 + d] : -lam1[d];

        const float lo = lOm[d];
        const float lam_Om = lo * lo;
        const float lg_ = lGa[d];
        const float lam_Ga = lg_ * lg_ + EPS_;
        const float tau_a = fabsf(tau_p[0]);

        const float t0 = t[0];
        const float dt = t[delta] - t0;

        const float amp = expf(re * dt);
        const float ph  = im * dt;
        const int td = delta * DV_ + d;
        ws[OFF_KER + td] = amp * cosf(ph);
        ws[OFF_KEI + td] = amp * sinf(ph);

        const float e2  = expf(2.0f * re * dt);
        const float vij = lam_Ga * e2 + lam_Om * (e2 - 1.0f) / (2.0f * (re - EPS_));
        ws[OFF_A   + td] = expf(-tau_a * logf(vij));
        ws[OFF_INV + td] = 1.0f / (vij + lam_Ga);

        if (delta == 0) {
            const float eta = 1.0f / (1.0f + expf(-eta_p[d]));
            const float g   = 1.0f / (1.0f + expf(-eta));
            ws[OFF_ETA + d] = eta;
            ws[OFF_G   + d] = g;
            const float h  = t[1] - t0;
            const float ma = expf(re * h);
            ws[OFF_MR + d] = ma * cosf(im * h);
            ws[OFF_MI + d] = ma * sinf(im * h);
            out[OUT_LAMH + d]       = re;
            out[OUT_LAMH + DV_ + d] = im;
        }
        return;
    }

    // ---------------- QKV branch (k-split across 4 waves) ----------------
    const int row = (int)blockIdx.x;        // b*N + n
    const int b = row >> 8, n = row & (N_ - 1);

    __shared__ float x[6][DE_];
    __shared__ float red[4][6][DV_];

    if (tid < DE_) {
        x[0][tid] = Zq[((size_t)(b*2+0)*N_ + n)*DE_ + tid];
        x[1][tid] = Zq[((size_t)(b*2+1)*N_ + n)*DE_ + tid];
        x[2][tid] = Zk[((size_t)(b*2+0)*N_ + n)*DE_ + tid];
        x[3][tid] = Zk[((size_t)(b*2+1)*N_ + n)*DE_ + tid];
        x[4][tid] = Zv[((size_t)(b*2+0)*N_ + n)*DE_ + tid];
        x[5][tid] = Zv[((size_t)(b*2+1)*N_ + n)*DE_ + tid];
    }
    __syncthreads();

    const int w = tid >> 6;                 // k-chunk: k in [32w, 32w+32)
    const int d = tid & 63;
    float aqr = 0.f, aqi = 0.f, akr = 0.f, aki = 0.f, avr = 0.f, avi = 0.f;
    const int k0 = w * 32;
    #pragma unroll 4
    for (int kk = 0; kk < 32; ++kk) {
        const int k = k0 + kk;
        const float xqr = x[0][k], xqi = x[1][k];
        const float xkr = x[2][k], xki = x[3][k];
        const float xvr = x[4][k], xvi = x[5][k];
        float wr, wi;
        wr = Wqr[k*DV_ + d]; wi = Wqi[k*DV_ + d];
        aqr += xqr*wr - xqi*wi; aqi += xqr*wi + xqi*wr;
        wr = Wkr[k*DV_ + d]; wi = Wki[k*DV_ + d];
        akr += xkr*wr - xki*wi; aki += xkr*wi + xki*wr;
        wr = Wvr[k*DV_ + d]; wi = Wvi[k*DV_ + d];
        avr += xvr*wr - xvi*wi; avi += xvr*wi + xvi*wr;
    }
    red[w][0][d] = aqr; red[w][1][d] = aqi;
    red[w][2][d] = akr; red[w][3][d] = aki;
    red[w][4][d] = avr; red[w][5][d] = avi;
    __syncthreads();

    if (tid < DV_) {
        const int o = row * DV_ + tid;
        ws[OFF_QR + o] = red[0][0][tid]+red[1][0][tid]+red[2][0][tid]+red[3][0][tid] + bqr[tid];
        ws[OFF_QI + o] = red[0][1][tid]+red[1][1][tid]+red[2][1][tid]+red[3][1][tid] + bqi[tid];
        ws[OFF_KR + o] = red[0][2][tid]+red[1][2][tid]+red[2][2][tid]+red[3][2][tid] + bkr[tid];
        ws[OFF_KI + o] = red[0][3][tid]+red[1][3][tid]+red[2][3][tid]+red[3][3][tid] + bki[tid];
        ws[OFF_VR + o] = red[0][4][tid]+red[1][4][tid]+red[2][4][tid]+red[3][4][tid] + bvr[tid];
        ws[OFF_VI + o] = red[0][5][tid]+red[1][5][tid]+red[2][5][tid]+red[3][5][tid] + bvi[tid];
    }
}

// =====================================================================
// Kernel 2: R8 structure EXACTLY, single variable changed: the two
// dependency-free zero-fill sweeps (Zhat upper region, Qij upper region)
// moved to the TOP of the kernel, so their store bursts drain while P1's
// dependent-load chain stalls the waves (in-block store/compute overlap).
// =====================================================================
__global__ __launch_bounds__(256) void k_main2(
    const float* __restrict__ ws, float* __restrict__ out,
    const float* __restrict__ Wpr, const float* __restrict__ Wpi,
    const float* __restrict__ bpr, const float* __restrict__ bpi,
    const float* __restrict__ nf_p, const float* __restrict__ tau_p,
    const float* __restrict__ nu_p)
{
    const int vb = (int)blockIdx.x;
    const int b = vb & 3;
    const int i = (N_ - 1) - (vb >> 2);     // heavy rows dispatch first
    const int row = b * N_ + i;
    const int tid = (int)threadIdx.x;
    const int wv = tid >> 6;
    const int l = tid & 63;
    const int g = l >> 4;
    const int q16 = l & 15;
    const int dq = q16 * 4;

    __shared__ float wl[N_];
    __shared__ f32x4 redS[4][16];
    __shared__ f32x4 redR[4][16];
    __shared__ f32x4 redI[4][16];
    __shared__ float ppr_s[DV_], ppi_s[DV_];

    const float nf    = nf_p[0];
    const float tau_a = fabsf(tau_p[0]);
    const float nu_a  = fabsf(nu_p[0]);

    const int nfull = (i + 1) >> 2;
    const int tail  = (i + 1) & 3;
    const f32x4 z4 = {0.f,0.f,0.f,0.f};

    float* qij = out + OUT_QIJ + (size_t)row * N_ * DV_;
    float* zro = out + OUT_ZHAT + ((size_t)(b*2+0)*N_ + i) * N_ * DV_;
    float* zio = out + OUT_ZHAT + ((size_t)(b*2+1)*N_ + i) * N_ * DV_;

    // ---- FRONT-LOADED zero regions (no dependencies; store bursts that
    //      the memory system drains while P1's load chain stalls) ----
    {
        const int jz0 = 4 * (nfull + (tail ? 1 : 0));
        const int nq = (N_ - jz0) * 16;
        for (int u = tid; u < nq; u += 256) {
            const int o = jz0*DV_ + u*4;
            st4(zro + o, z4);
            st4(zio + o, z4);
            st4(qij + o, z4);
        }
    }

    const f32x4 qr4 = ld4(ws + OFF_QR + row*DV_ + dq);
    const f32x4 qi4 = ld4(ws + OFF_QI + row*DV_ + dq);

    // ---- P1: dist -> w[j]; Zhat stream; accumulate Z and ev ----
    f32x4 s4  = {0.f,0.f,0.f,0.f};
    f32x4 evr = {0.f,0.f,0.f,0.f};
    f32x4 evi = {0.f,0.f,0.f,0.f};
    #pragma unroll 2
    for (int T = wv; T < nfull; T += 4) {
        const int j = 4*T + g;
        const int o = j*DV_ + dq;
        const int td = (i - j)*DV_ + dq;
        const f32x4 ker = ld4(ws + OFF_KER + td);
        const f32x4 kei = ld4(ws + OFF_KEI + td);
        const f32x4 vnv = ld4(ws + OFF_INV + td);
        const f32x4 a4  = ld4(ws + OFF_A   + td);
        const int kj = (b*N_ + j)*DV_ + dq;
        const f32x4 kr = ld4(ws + OFF_KR + kj);
        const f32x4 ki = ld4(ws + OFF_KI + kj);
        const f32x4 vr = ld4(ws + OFF_VR + kj);
        const f32x4 vi = ld4(ws + OFF_VI + kj);
        const f32x4 rr = qr4 - (ker*kr - kei*ki);
        const f32x4 ri = qi4 - (ker*ki + kei*kr);
        const f32x4 mah = (rr*rr + ri*ri) * vnv;
        float ds = mah[0] + mah[1] + mah[2] + mah[3];
        ds += __shfl_xor(ds, 1);
        ds += __shfl_xor(ds, 2);
        ds += __shfl_xor(ds, 4);
        ds += __shfl_xor(ds, 8);
        const float wj = expf(-tau_a * logf(nf + nu_a*ds + EPS_));
        if (q16 == 0) wl[j] = wj;
        const f32x4 zr = ker*vr - kei*vi;
        const f32x4 zi = ker*vi + kei*vr;
        st4(zro + o, zr);
        st4(zio + o, zi);
        const f32x4 qn = a4 * wj;
        s4  += qn;
        evr += qn * zr;
        evi += qn * zi;
    }
    if (tail && ((nfull & 3) == wv)) {
        const int j = 4*nfull + g;
        const int o = j*DV_ + dq;
        const bool act = (g < tail);
        const int td = (act ? (i - j) : 0)*DV_ + dq;
        const f32x4 ker = ld4(ws + OFF_KER + td);
        const f32x4 kei = ld4(ws + OFF_KEI + td);
        const f32x4 vnv = ld4(ws + OFF_INV + td);
        const f32x4 a4  = ld4(ws + OFF_A   + td);
        const int kj = (b*N_ + (act ? j : 0))*DV_ + dq;
        const f32x4 kr = ld4(ws + OFF_KR + kj);
        const f32x4 ki = ld4(ws + OFF_KI + kj);
        const f32x4 vr = ld4(ws + OFF_VR + kj);
        const f32x4 vi = ld4(ws + OFF_VI + kj);
        const f32x4 rr = qr4 - (ker*kr - kei*ki);
        const f32x4 ri = qi4 - (ker*ki + kei*kr);
        const f32x4 mah = (rr*rr + ri*ri) * vnv;
        float ds = mah[0] + mah[1] + mah[2] + mah[3];
        ds += __shfl_xor(ds, 1);
        ds += __shfl_xor(ds, 2);
        ds += __shfl_xor(ds, 4);
        ds += __shfl_xor(ds, 8);
        if (act) {
            const float wj = expf(-tau_a * logf(nf + nu_a*ds + EPS_));
            if (q16 == 0) wl[j] = wj;
            const f32x4 zr = ker*vr - kei*vi;
            const f32x4 zi = ker*vi + kei*vr;
            st4(zro + o, zr);
            st4(zio + o, zi);
            const f32x4 qn = a4 * wj;
            s4  += qn;
            evr += qn * zr;
            evi += qn * zi;
        } else {
            st4(zro + o, z4);
            st4(zio + o, z4);
        }
    }

    // reduce s4 / evr / evi across the 4 g-slots then across waves
    #pragma unroll
    for (int mask = 16; mask <= 32; mask <<= 1) {
        #pragma unroll
        for (int c = 0; c < 4; ++c) {
            s4[c]  += __shfl_xor(s4[c],  mask);
            evr[c] += __shfl_xor(evr[c], mask);
            evi[c] += __shfl_xor(evi[c], mask);
        }
    }
    if (g == 0) { redS[wv][q16] = s4; redR[wv][q16] = evr; redI[wv][q16] = evi; }
    __syncthreads();
    const f32x4 Z = redS[0][q16] + redS[1][q16] + redS[2][q16] + redS[3][q16];
    const f32x4 one = {1.f,1.f,1.f,1.f};
    const f32x4 invZ = one / Z;

    // ---- P3: Qij stream ----
    #pragma unroll 2
    for (int T = wv; T < nfull; T += 4) {
        const int j = 4*T + g;
        const int o = j*DV_ + dq;
        const int td = (i - j)*DV_ + dq;
        const f32x4 q4 = ld4(ws + OFF_A + td) * wl[j] * invZ;
        st4(qij + o, q4);
    }
    if (tail && ((nfull & 3) == wv)) {
        const int j = 4*nfull + g;
        const int o = j*DV_ + dq;
        if (g < tail) {
            const int td = (i - j)*DV_ + dq;
            const f32x4 q4 = ld4(ws + OFF_A + td) * wl[j] * invZ;
            st4(qij + o, q4);
        } else {
            st4(qij + o, z4);
        }
    }

    // ---- epilogue: est_latent + pp ----
    if (tid < 16) {
        const f32x4 Zt = redS[0][tid] + redS[1][tid] + redS[2][tid] + redS[3][tid];
        const f32x4 iZ = one / Zt;
        const f32x4 Evr = (redR[0][tid] + redR[1][tid] + redR[2][tid] + redR[3][tid]) * iZ;
        const f32x4 Evi = (redI[0][tid] + redI[1][tid] + redI[2][tid] + redI[3][tid]) * iZ;
        const int dq2 = tid * 4;
        const f32x4 vr  = ld4(ws + OFF_VR + row*DV_ + dq2);
        const f32x4 vi  = ld4(ws + OFF_VI + row*DV_ + dq2);
        const f32x4 eta = ld4(ws + OFF_ETA + dq2);
        const f32x4 gg  = ld4(ws + OFF_G + dq2);
        const f32x4 elr = (1.0f - eta)*vr + gg*Evr;
        const f32x4 eli = (1.0f - eta)*vi + gg*Evi;
        st4(out + OUT_EL + ((size_t)(b*2+0)*N_ + i)*DV_ + dq2, elr);
        st4(out + OUT_EL + ((size_t)(b*2+1)*N_ + i)*DV_ + dq2, eli);
        const f32x4 mr = ld4(ws + OFF_MR + dq2);
        const f32x4 mi = ld4(ws + OFF_MI + dq2);
        st4(ppr_s + dq2, mr*elr - mi*eli);
        st4(ppi_s + dq2, mr*eli + mi*elr);
    }
    __syncthreads();

    // ---- fused output projection ----
    if (tid < DE_) {
        const int e = tid;
        float ar = bpr[e], ai = bpi[e];
        #pragma unroll 8
        for (int dd = 0; dd < DV_; ++dd) {
            const float wr = Wpr[dd*DE_ + e], wi = Wpi[dd*DE_ + e];
            const float r = ppr_s[dd], im = ppi_s[dd];
            ar += r*wr - im*wi;
            ai += r*wi + im*wr;
        }
        out[OUT_OUT + ((size_t)(b*2+0)*N_ + i)*DE_ + e] = ar;
        out[OUT_OUT + ((size_t)(b*2+1)*N_ + i)*DE_ + e] = ai;
    }
}

// =====================================================================
extern "C" void kernel_launch(void* const* d_in, const int* in_sizes, int n_in,
                              void* d_out, int out_size, void* d_ws, size_t ws_size,
                              hipStream_t stream)
{
    const float* Zq   = (const float*)d_in[0];
    const float* Zk   = (const float*)d_in[1];
    const float* Zv   = (const float*)d_in[2];
    const float* t    = (const float*)d_in[3];
    const float* Wqr  = (const float*)d_in[4];
    const float* Wqi  = (const float*)d_in[5];
    const float* bqr  = (const float*)d_in[6];
    const float* bqi  = (const float*)d_in[7];
    const float* Wkr  = (const float*)d_in[8];
    const float* Wki  = (const float*)d_in[9];
    const float* bkr  = (const float*)d_in[10];
    const float* bki  = (const float*)d_in[11];
    const float* Wvr  = (const float*)d_in[12];
    const float* Wvi  = (const float*)d_in[13];
    const float* bvr  = (const float*)d_in[14];
    const float* bvi  = (const float*)d_in[15];
    const float* Wpr  = (const float*)d_in[16];
    const float* Wpi  = (const float*)d_in[17];
    const float* bpr  = (const float*)d_in[18];
    const float* bpi  = (const float*)d_in[19];
    const float* lam1 = (const float*)d_in[20];
    const float* lOm  = (const float*)d_in[21];
    const float* lGa  = (const float*)d_in[22];
    const float* nf   = (const float*)d_in[23];
    const float* tau  = (const float*)d_in[24];
    const float* nu   = (const float*)d_in[25];
    const float* etap = (const float*)d_in[26];

    float* ws  = (float*)d_ws;
    float* out = (float*)d_out;

    k_pre<<<1024 + 64, 256, 0, stream>>>(Zq, Zk, Zv,
                                         Wqr, Wqi, bqr, bqi,
                                         Wkr, Wki, bkr, bki,
                                         Wvr, Wvi, bvr, bvi,
                                         t, lam1, lOm, lGa, etap, tau, ws, out);
    k_main2<<<B_*N_, 256, 0, stream>>>(ws, out, Wpr, Wpi, bpr, bpi, nf, tau, nu);
}